// Round 1
// baseline (289.434 us; speedup 1.0000x reference)
//
#include <hip/hip_runtime.h>

#define B_ 4
#define CK 64
#define CV 512
#define HW_ 900
#define THW 7200
#define MT 96
#define QB 64
#define CVB 128

typedef __attribute__((ext_vector_type(4))) float f32x4;
typedef __attribute__((ext_vector_type(4))) float float4_;
typedef __attribute__((ext_vector_type(8))) short s16x8;
typedef __attribute__((ext_vector_type(4))) short s16x4;

__device__ __forceinline__ short f2bf(float f) {
  union { float f; unsigned u; } x; x.f = f;
  unsigned u = x.u;
  return (short)((u + 0x7fffu + ((u >> 16) & 1u)) >> 16);  // RNE to bf16
}

// mk [B][CK][THW] f32  ->  mkT [B][THW][CK] bf16,  asq[b][m] = 0.125*log2e*sum_k mk^2
__global__ __launch_bounds__(256) void prep_mk_kernel(const float* __restrict__ mk,
                                                      short* __restrict__ mkT,
                                                      float* __restrict__ asq) {
  int idx = blockIdx.x * 256 + threadIdx.x;
  if (idx >= B_ * THW) return;
  int b = idx / THW, m = idx - b * THW;
  const float* src = mk + (size_t)b * CK * THW + m;
  short row[CK];
  float acc = 0.f;
#pragma unroll
  for (int k = 0; k < CK; ++k) {
    float v = src[(size_t)k * THW];
    acc += v * v;
    row[k] = f2bf(v);
  }
  short* dst = mkT + (size_t)idx * CK;
#pragma unroll
  for (int c = 0; c < CK / 8; ++c)
    *reinterpret_cast<s16x8*>(dst + c * 8) = *reinterpret_cast<s16x8*>(row + c * 8);
  asq[idx] = acc * 0.18033688011112042f;  // 0.125 * log2(e)
}

// qk -> bf16 scaled by 0.25*log2(e)  (so logits are in exp2 units; scale is folded)
__global__ __launch_bounds__(256) void prep_qk_kernel(const float* __restrict__ qk,
                                                      short* __restrict__ qkb) {
  int i = blockIdx.x * 256 + threadIdx.x;
  if (i < B_ * CK * HW_) qkb[i] = f2bf(qk[i] * 0.36067376022224085f);
}

// mv f32 -> bf16 (same [B][CV][THW] layout)
__global__ __launch_bounds__(256) void prep_mv_kernel(const float4_* __restrict__ mv,
                                                      short* __restrict__ mvb) {
  int i = blockIdx.x * 256 + threadIdx.x;
  const int n4 = B_ * CV * THW / 4;
  if (i >= n4) return;
  float4_ v = mv[i];
  s16x4 o;
  o[0] = f2bf(v[0]); o[1] = f2bf(v[1]); o[2] = f2bf(v[2]); o[3] = f2bf(v[3]);
  *reinterpret_cast<s16x4*>(mvb + (size_t)i * 4) = o;
}

// qv -> out channels [CV, 2*CV)
__global__ __launch_bounds__(256) void copy_qv_kernel(const float4_* __restrict__ qv,
                                                      float* __restrict__ out) {
  int i = blockIdx.x * 256 + threadIdx.x;
  const int n4 = B_ * CV * HW_ / 4;
  if (i >= n4) return;
  const int perb = CV * HW_ / 4;
  int b = i / perb, r = i - b * perb;
  float4_ v = qv[i];
  *reinterpret_cast<float4_*>(out + (size_t)b * 2 * CV * HW_ + CV * HW_ + (size_t)r * 4) = v;
}

// Fused: logits MFMA -> exp2 -> readout MFMA, unnormalized + per-block denominator.
// grid (15 qblocks, 4 cv-chunks, B), 256 threads (4 waves; wave w owns q-slice w*16..+16, all 128 cv)
__global__ __launch_bounds__(256, 1) void attn_kernel(const short* __restrict__ mkT,
                                                      const short* __restrict__ qkb,
                                                      const short* __restrict__ mvb,
                                                      const float* __restrict__ asq,
                                                      float* __restrict__ out) {
  __shared__ short mv_t[CVB][MT + 16];    // [128][112] bf16
  __shared__ short mk_t[MT][CK + 16];     // [96][80] bf16
  __shared__ short e_t[4][16][MT + 16];   // per-wave E tile [q-local][m]
  __shared__ float asq_t[MT];

  const int tid = threadIdx.x;
  const int wave = tid >> 6, lane = tid & 63;
  const int g = lane >> 4, c = lane & 15;
  const int qb = blockIdx.x, cvc = blockIdx.y, b = blockIdx.z;
  const int q = qb * QB + wave * 16 + c;   // this lane's output column
  const int cv0 = cvc * CVB;

  // hoist qk B-fragments: B[k][n], lane holds k = ks*32 + g*8 + j, n = c
  s16x8 qf[2];
  {
    const short* qs = qkb + (size_t)b * CK * HW_;
#pragma unroll
    for (int ks = 0; ks < 2; ++ks) {
#pragma unroll
      for (int j = 0; j < 8; ++j) {
        int k = ks * 32 + g * 8 + j;
        qf[ks][j] = (q < HW_) ? qs[(size_t)k * HW_ + q] : (short)0;
      }
    }
  }

  f32x4 acc[8];
#pragma unroll
  for (int i = 0; i < 8; ++i) acc[i] = (f32x4){0.f, 0.f, 0.f, 0.f};
  float denom = 0.f;

  const short* mksrc = mkT + (size_t)b * THW * CK;
  const short* mvsrc = mvb + ((size_t)b * CV + cv0) * THW;
  const float* asrc = asq + (size_t)b * THW;

  for (int it = 0; it < THW / MT; ++it) {  // 75 iterations
    const int m0 = it * MT;
    // ---- stage: mk tile (contiguous 96x64), mv tile (128x96), asq ----
    {
      const short* s0 = mksrc + (size_t)m0 * CK;
#pragma unroll
      for (int p = 0; p < 3; ++p) {
        int ch = tid + p * 256;
        int r = ch >> 3, c8 = (ch & 7) * 8;
        *reinterpret_cast<s16x8*>(&mk_t[r][c8]) =
            *reinterpret_cast<const s16x8*>(s0 + r * CK + c8);
      }
#pragma unroll
      for (int p = 0; p < 6; ++p) {
        int ch = tid + p * 256;
        int r = ch / 12, c8 = (ch % 12) * 8;
        *reinterpret_cast<s16x8*>(&mv_t[r][c8]) =
            *reinterpret_cast<const s16x8*>(mvsrc + (size_t)r * THW + m0 + c8);
      }
      if (tid < MT) asq_t[tid] = asrc[m0 + tid];
    }
    __syncthreads();

    // ---- S = mkT_tile(96m x 64k) x qk(64k x 16q), then E = exp2(S - asq) ----
#pragma unroll
    for (int mf = 0; mf < 6; ++mf) {
      f32x4 s = (f32x4){0.f, 0.f, 0.f, 0.f};
#pragma unroll
      for (int ks = 0; ks < 2; ++ks) {
        s16x8 a = *reinterpret_cast<const s16x8*>(&mk_t[mf * 16 + c][ks * 32 + g * 8]);
        s = __builtin_amdgcn_mfma_f32_16x16x32_bf16(a, qf[ks], s, 0, 0, 0);
      }
      const int mb = mf * 16 + g * 4;  // D row = g*4 + r (+ mf*16), col = c
      s16x4 e4;
#pragma unroll
      for (int r = 0; r < 4; ++r) {
        float e = exp2f(s[r] - asq_t[mb + r]);
        denom += e;
        e4[r] = f2bf(e);
      }
      *reinterpret_cast<s16x4*>(&e_t[wave][c][mb]) = e4;
    }
    __syncthreads();  // safety barrier round 0 (e_t is wave-private; candidate removal)

    // ---- readout: acc(128cv x 16q) += mv_tile(128cv x 96m) x E(96m x 16q) ----
#pragma unroll
    for (int ks = 0; ks < 3; ++ks) {
      s16x8 bfr = *reinterpret_cast<const s16x8*>(&e_t[wave][c][ks * 32 + g * 8]);
#pragma unroll
      for (int cf = 0; cf < 8; ++cf) {
        s16x8 afr = *reinterpret_cast<const s16x8*>(&mv_t[cf * 16 + c][ks * 32 + g * 8]);
        acc[cf] = __builtin_amdgcn_mfma_f32_16x16x32_bf16(afr, bfr, acc[cf], 0, 0, 0);
      }
    }
    __syncthreads();
  }

  // denominator: combine the 4 lane-groups holding disjoint m-subsets of column q
  denom += __shfl_xor(denom, 16);
  denom += __shfl_xor(denom, 32);
  const float inv = 1.f / denom;

  if (q < HW_) {
    float* ob = out + (size_t)b * (2 * CV * HW_) + (size_t)(cv0 + g * 4) * HW_ + q;
#pragma unroll
    for (int cf = 0; cf < 8; ++cf)
#pragma unroll
      for (int r = 0; r < 4; ++r)
        ob[(size_t)(cf * 16 + r) * HW_] = acc[cf][r] * inv;
  }
}

extern "C" void kernel_launch(void* const* d_in, const int* in_sizes, int n_in,
                              void* d_out, int out_size, void* d_ws, size_t ws_size,
                              hipStream_t stream) {
  const float* mk = (const float*)d_in[0];
  const float* qk = (const float*)d_in[1];
  const float* mv = (const float*)d_in[2];
  const float* qv = (const float*)d_in[3];
  float* out = (float*)d_out;

  // workspace layout (33.75 MB total)
  char* ws = (char*)d_ws;
  short* mvb = (short*)ws;                    // 4*512*7200*2 = 29,491,200
  short* mkT = (short*)(ws + 29491200);       // 4*7200*64*2  =  3,686,400
  short* qkb = (short*)(ws + 33177600);       // 4*64*900*2   =    460,800
  float* asq = (float*)(ws + 33638400);       // 4*7200*4     =    115,200

  prep_mk_kernel<<<dim3((B_ * THW + 255) / 256), dim3(256), 0, stream>>>(mk, mkT, asq);
  prep_qk_kernel<<<dim3((B_ * CK * HW_ + 255) / 256), dim3(256), 0, stream>>>(qk, qkb);
  prep_mv_kernel<<<dim3((B_ * CV * THW / 4 + 255) / 256), dim3(256), 0, stream>>>(
      (const float4_*)mv, mvb);
  attn_kernel<<<dim3(15, 4, B_), dim3(256), 0, stream>>>(mkT, qkb, mvb, asq, out);
  copy_qv_kernel<<<dim3((B_ * CV * HW_ / 4 + 255) / 256), dim3(256), 0, stream>>>(
      (const float4_*)qv, out);
}

// Round 4
// 237.233 us; speedup vs baseline: 1.2200x; 1.2200x over previous
//
#include <hip/hip_runtime.h>

#define B_ 4
#define CK 64
#define CV 512
#define HW_ 900
#define THW 7200
#define MT 96
#define QB 64
#define CVB 128
#define NS 3             // m-splits
#define MSPL (THW / NS)  // 2400
#define NIT (MSPL / MT)  // 25
#define MVP (MT + 8)     // 104 shorts: 208B row stride (13 quads -> phase-optimal b128)
#define MKP (CK + 8)     // 72 shorts: 144B row stride (9 quads)

typedef __attribute__((ext_vector_type(4))) float f32x4;
typedef __attribute__((ext_vector_type(4))) float float4_;
typedef __attribute__((ext_vector_type(8))) short s16x8;
typedef __attribute__((ext_vector_type(4))) short s16x4;

__device__ __forceinline__ short f2bf(float f) {
  union { float f; unsigned u; } x; x.f = f;
  unsigned u = x.u;
  return (short)((u + 0x7fffu + ((u >> 16) & 1u)) >> 16);  // RNE to bf16
}

// Fused prep: [A] mk->mkT bf16 + asq  [B] qk->bf16*0.25*log2e  [C] mv->bf16  [D] qv->out
#define NBLK_A 113
#define NBLK_B 900
#define NBLK_C 14400
#define NBLK_D 1800
__global__ __launch_bounds__(256) void prep_kernel(const float* __restrict__ mk,
                                                   const float* __restrict__ qk,
                                                   const float* __restrict__ mv,
                                                   const float* __restrict__ qv,
                                                   short* __restrict__ mkT,
                                                   short* __restrict__ qkb,
                                                   short* __restrict__ mvb,
                                                   float* __restrict__ asq,
                                                   float* __restrict__ out) {
  int bid = blockIdx.x;
  if (bid < NBLK_A) {  // mk transpose + |a|^2
    int idx = bid * 256 + threadIdx.x;
    if (idx >= B_ * THW) return;
    int b = idx / THW, m = idx - b * THW;
    const float* src = mk + (size_t)b * CK * THW + m;
    short row[CK];
    float acc = 0.f;
#pragma unroll
    for (int k = 0; k < CK; ++k) {
      float v = src[(size_t)k * THW];
      acc += v * v;
      row[k] = f2bf(v);
    }
    short* dst = mkT + (size_t)idx * CK;
#pragma unroll
    for (int c = 0; c < CK / 8; ++c)
      *reinterpret_cast<s16x8*>(dst + c * 8) = *reinterpret_cast<s16x8*>(row + c * 8);
    asq[idx] = acc * 0.18033688011112042f;  // 0.125 * log2(e)
  } else if (bid < NBLK_A + NBLK_B) {  // qk cast (exp2-units scale folded)
    int i = (bid - NBLK_A) * 256 + threadIdx.x;
    if (i < B_ * CK * HW_) qkb[i] = f2bf(qk[i] * 0.36067376022224085f);
  } else if (bid < NBLK_A + NBLK_B + NBLK_C) {  // mv cast
    int i = (bid - (NBLK_A + NBLK_B)) * 256 + threadIdx.x;
    float4_ v = reinterpret_cast<const float4_*>(mv)[i];
    s16x4 o;
    o[0] = f2bf(v[0]); o[1] = f2bf(v[1]); o[2] = f2bf(v[2]); o[3] = f2bf(v[3]);
    *reinterpret_cast<s16x4*>(mvb + (size_t)i * 4) = o;
  } else {  // qv passthrough -> out channels [CV, 2CV)
    int i = (bid - (NBLK_A + NBLK_B + NBLK_C)) * 256 + threadIdx.x;
    const int perb = CV * HW_ / 4;
    int b = i / perb, r = i - b * perb;
    float4_ v = reinterpret_cast<const float4_*>(qv)[i];
    *reinterpret_cast<float4_*>(out + (size_t)b * 2 * CV * HW_ + CV * HW_ + (size_t)r * 4) = v;
  }
}

// Fused attention over one m-split: logits MFMA -> exp2 -> readout MFMA.
// grid (15 qb, 4 cvc * NS splits, B). Writes unnormalized partial numerator + denom.
__global__ __launch_bounds__(256, 3) void attn_kernel(const short* __restrict__ mkT,
                                                      const short* __restrict__ qkb,
                                                      const short* __restrict__ mvb,
                                                      const float* __restrict__ asq,
                                                      float* __restrict__ part,
                                                      float* __restrict__ denomp) {
  __shared__ short mv_t[CVB][MVP];    // 26,624 B
  __shared__ short mk_t[MT][MKP];     // 13,824 B
  __shared__ short e_t[4][16][MVP];   // 13,312 B (wave-private)
  __shared__ float asq_t[MT];         // 384 B   => 54,144 B total -> 3 blocks/CU

  const int tid = threadIdx.x;
  const int wave = tid >> 6, lane = tid & 63;
  const int g = lane >> 4, c = lane & 15;
  const int qb = blockIdx.x;
  const int cvc = blockIdx.y & 3, s = blockIdx.y >> 2;
  const int b = blockIdx.z;
  const int q = qb * QB + wave * 16 + c;
  const int cv0 = cvc * CVB;

  // hoist qk B-fragments: lane holds B[k = ks*32 + g*8 + j][n = c]
  s16x8 qf[2];
  {
    const short* qs = qkb + (size_t)b * CK * HW_;
#pragma unroll
    for (int ks = 0; ks < 2; ++ks)
#pragma unroll
      for (int j = 0; j < 8; ++j)
        qf[ks][j] = (q < HW_) ? qs[(size_t)(ks * 32 + g * 8 + j) * HW_ + q] : (short)0;
  }

  f32x4 acc[8];
#pragma unroll
  for (int i = 0; i < 8; ++i) acc[i] = (f32x4){0.f, 0.f, 0.f, 0.f};
  float denom = 0.f;

  const short* mksrc = mkT + (size_t)b * THW * CK;
  const short* mvsrc = mvb + ((size_t)b * CV + cv0) * THW;
  const float* asrc = asq + (size_t)b * THW;

  for (int it = 0; it < NIT; ++it) {
    const int m0 = s * MSPL + it * MT;
    {  // stage mk (96x64), mv (128x96), asq
      const short* s0 = mksrc + (size_t)m0 * CK;
#pragma unroll
      for (int p = 0; p < 3; ++p) {
        int ch = tid + p * 256;
        int r = ch >> 3, c8 = (ch & 7) * 8;
        *reinterpret_cast<s16x8*>(&mk_t[r][c8]) =
            *reinterpret_cast<const s16x8*>(s0 + r * CK + c8);
      }
#pragma unroll
      for (int p = 0; p < 6; ++p) {
        int ch = tid + p * 256;
        int r = ch / 12, c8 = (ch % 12) * 8;
        *reinterpret_cast<s16x8*>(&mv_t[r][c8]) =
            *reinterpret_cast<const s16x8*>(mvsrc + (size_t)r * THW + m0 + c8);
      }
      if (tid < MT) asq_t[tid] = asrc[m0 + tid];
    }
    __syncthreads();

    // S = mk_tile(96m x 64k) x qk(64k x 16q); E = exp2(S - asq)
#pragma unroll
    for (int mf = 0; mf < 6; ++mf) {
      f32x4 sa = (f32x4){0.f, 0.f, 0.f, 0.f};
#pragma unroll
      for (int ks = 0; ks < 2; ++ks) {
        s16x8 a = *reinterpret_cast<const s16x8*>(&mk_t[mf * 16 + c][ks * 32 + g * 8]);
        sa = __builtin_amdgcn_mfma_f32_16x16x32_bf16(a, qf[ks], sa, 0, 0, 0);
      }
      const int mb = mf * 16 + g * 4;
      s16x4 e4;
#pragma unroll
      for (int r = 0; r < 4; ++r) {
        float e = exp2f(sa[r] - asq_t[mb + r]);
        denom += e;
        e4[r] = f2bf(e);
      }
      *reinterpret_cast<s16x4*>(&e_t[wave][c][mb]) = e4;  // wave-private, no barrier
    }

    // acc(128cv x 16q) += mv_tile(128cv x 96m) x E(96m x 16q)
#pragma unroll
    for (int ks = 0; ks < 3; ++ks) {
      s16x8 bfr = *reinterpret_cast<const s16x8*>(&e_t[wave][c][ks * 32 + g * 8]);
#pragma unroll
      for (int cf = 0; cf < 8; ++cf) {
        s16x8 afr = *reinterpret_cast<const s16x8*>(&mv_t[cf * 16 + c][ks * 32 + g * 8]);
        acc[cf] = __builtin_amdgcn_mfma_f32_16x16x32_bf16(afr, bfr, acc[cf], 0, 0, 0);
      }
    }
    __syncthreads();
  }

  denom += __shfl_xor(denom, 16);
  denom += __shfl_xor(denom, 32);
  if (cvc == 0 && lane < 16)
    denomp[((size_t)s * B_ + b) * 960 + qb * QB + wave * 16 + lane] = denom;

  float* pb = part + (size_t)(((s * B_ + b) * 4 + cvc) * 15 + qb) * 8192 + wave * 16 + c;
#pragma unroll
  for (int cf = 0; cf < 8; ++cf)
#pragma unroll
    for (int r = 0; r < 4; ++r)
      pb[(size_t)(cf * 16 + g * 4 + r) * 64] = acc[cf][r];
}

// Sum NS partials, normalize, write mem half of out.
__global__ __launch_bounds__(256) void finalize_kernel(const float* __restrict__ part,
                                                       const float* __restrict__ denomp,
                                                       float* __restrict__ out) {
  int t = blockIdx.x * 256 + threadIdx.x;  // 491,520 threads
  int q4 = t & 15;
  int cvl = (t >> 4) & 127;
  int r1 = t >> 11;
  int qb = r1 % 15;
  int r2 = r1 / 15;
  int cvc = r2 & 3;
  int b = r2 >> 2;
  int q0 = qb * QB + q4 * 4;
  if (q0 >= HW_) return;
  const size_t sstr = (size_t)B_ * 4 * 15 * 8192;
  size_t base = (size_t)((b * 4 + cvc) * 15 + qb) * 8192 + cvl * 64 + q4 * 4;
  f32x4 p = *reinterpret_cast<const f32x4*>(part + base);
  f32x4 p1 = *reinterpret_cast<const f32x4*>(part + base + sstr);
  f32x4 p2 = *reinterpret_cast<const f32x4*>(part + base + 2 * sstr);
  p = p + p1 + p2;
  const float* dp = denomp + (size_t)b * 960 + q0;
  f32x4 d = *reinterpret_cast<const f32x4*>(dp) +
            *reinterpret_cast<const f32x4*>(dp + B_ * 960) +
            *reinterpret_cast<const f32x4*>(dp + 2 * B_ * 960);
  f32x4 o;
#pragma unroll
  for (int j = 0; j < 4; ++j) o[j] = p[j] / d[j];
  *reinterpret_cast<f32x4*>(out + (size_t)b * 2 * CV * HW_ +
                            (size_t)(cvc * CVB + cvl) * HW_ + q0) = o;
}

extern "C" void kernel_launch(void* const* d_in, const int* in_sizes, int n_in,
                              void* d_out, int out_size, void* d_ws, size_t ws_size,
                              hipStream_t stream) {
  const float* mk = (const float*)d_in[0];
  const float* qk = (const float*)d_in[1];
  const float* mv = (const float*)d_in[2];
  const float* qv = (const float*)d_in[3];
  float* out = (float*)d_out;

  // workspace layout (57,392,640 B total)
  char* ws = (char*)d_ws;
  short* mvb   = (short*)ws;                   // 29,491,200
  short* mkT   = (short*)(ws + 29491200);      //  3,686,400
  short* qkb   = (short*)(ws + 33177600);      //    460,800
  float* asq   = (float*)(ws + 33638400);      //    115,200
  float* denomp= (float*)(ws + 33753600);      //     46,080 (NS*B*960 f32)
  float* part  = (float*)(ws + 33799680);      // 23,592,960 (720 blocks * 128*64 f32)

  prep_kernel<<<dim3(NBLK_A + NBLK_B + NBLK_C + NBLK_D), dim3(256), 0, stream>>>(
      mk, qk, mv, qv, mkT, qkb, mvb, asq, out);
  attn_kernel<<<dim3(15, 4 * NS, B_), dim3(256), 0, stream>>>(mkT, qkb, mvb, asq, part, denomp);
  finalize_kernel<<<dim3(1920), dim3(256), 0, stream>>>(part, denomp, out);
}